// Round 8
// baseline (1231.384 us; speedup 1.0000x reference)
//
#include <hip/hip_runtime.h>

// LieGroupDecoder MI355X — round 1c: split-bf16 MFMA conv stack, fp32 activations.
//
// Pipeline (single static path, ws need = 67MB):
//   lie_gemm(fp32, ->d_out as lieA) -> expm(->gfeat in ws) ->
//   conv0 fp32 GEMM (K=300, gfeat->d_out) ->
//   4x conv_mfma: im2col GEMM M=32768,N=512,K=1536 via 16x16x32 bf16 MFMA,
//     split-bf16 (hh+hl+lh, fp32 acc; ~1.5e-5 rel err). Activations stay fp32
//     between layers (d_out <-> ws ping-pong); hi/lo split happens in-register
//     during LDS staging. Weights pre-split to bf16 hi/lo pairs (wtrans_bf).
//
// MFMA layout notes: C/D mapping is HW-measured (col=lane&15,
// row=(lane>>4)*4+reg). A/B are loaded k-contiguous-8 per lane with the SAME
// k->(group,elem) map for both operands, so the result is invariant to the
// HW's internal per-lane k-order (k-permutation applied to both operands
// cancels in the contraction). Residual assumption: A-row/B-col = lane&15.
// LDS tiles use granule XOR swizzle  slot = g ^ ((row>>1)&3)  on BOTH write
// and read sides (involution; rule 21). Row stride is 64B=16 words so banks
// repeat every 4 rows; XOR on row bits 1..2 separates rows m..m+7 into
// distinct 16B slots -> 2-way aliasing on ds_read_b128 (free per m136).

typedef __attribute__((ext_vector_type(8))) short short8;
typedef __attribute__((ext_vector_type(4))) float f32x4;

#define NWS 16
#define ZD 512
#define MM 100
#define NCOUT 512

static __device__ __forceinline__ unsigned short f2bf(float f) {
    union { float f; unsigned u; } x; x.f = f;
    unsigned r = x.u + 0x7fffu + ((x.u >> 16) & 1u);  // RNE
    return (unsigned short)(r >> 16);
}
static __device__ __forceinline__ float bf2f(unsigned short b) {
    union { unsigned u; float f; } x; x.u = ((unsigned)b) << 16; return x.f;
}

// ------------------------------------------------------------- lie einsum GEMM
__global__ __launch_bounds__(256) void lie_gemm(const float* __restrict__ Z,
                                                const float* __restrict__ Basis,
                                                float* __restrict__ Out) {
    __shared__ float As[16][132];
    __shared__ float Bs[16][128];
    const int w = blockIdx.y;
    const int row0 = blockIdx.x * 128;
    const int tid = threadIdx.x;
    const int tx = tid & 15, ty = tid >> 4;
    float acc[8][8];
#pragma unroll
    for (int r = 0; r < 8; ++r)
#pragma unroll
        for (int c = 0; c < 8; ++c) acc[r][c] = 0.f;

    for (int k0 = 0; k0 < ZD; k0 += 16) {
#pragma unroll
        for (int ii = 0; ii < 8; ++ii) {
            int u = tid * 8 + ii;
            int kk = u & 15, m = u >> 4;
            As[kk][m] = Z[(size_t)((row0 + m) * NWS + w) * ZD + (k0 + kk)];
        }
#pragma unroll
        for (int ii = 0; ii < 8; ++ii) {
            int u = tid + ii * 256;
            int n = u & 127, kk = u >> 7;
            Bs[kk][n] = (n < MM) ? Basis[(size_t)(w * ZD + k0 + kk) * MM + n] : 0.f;
        }
        __syncthreads();
#pragma unroll
        for (int kk = 0; kk < 16; ++kk) {
            float a[8], b[8];
#pragma unroll
            for (int r = 0; r < 8; ++r) a[r] = As[kk][ty * 8 + r];
#pragma unroll
            for (int c = 0; c < 8; ++c) b[c] = Bs[kk][tx * 8 + c];
#pragma unroll
            for (int r = 0; r < 8; ++r)
#pragma unroll
                for (int c = 0; c < 8; ++c) acc[r][c] += a[r] * b[c];
        }
        __syncthreads();
    }
#pragma unroll
    for (int r = 0; r < 8; ++r) {
        int b = row0 + ty * 8 + r;
#pragma unroll
        for (int c = 0; c < 8; ++c) {
            int col = tx * 8 + c;
            if (col < MM) Out[(size_t)(b * NWS + w) * MM + col] = acc[r][c];
        }
    }
}

// ------------------------------------------------------------------ expm(10x10)
// 16 matrices/block; thread owns elem (i,j) of 8 matrices; A's col j in regs;
// P round-trips LDS per Taylor term. exp(A) = sum_{t=0..14} A^t/t!.
__global__ __launch_bounds__(256) void expm_kernel(const float* __restrict__ Ain,
                                                   float* __restrict__ Gout) {
    __shared__ float Pm[16][104];
    __shared__ float Am[16][104];
    const int tid = threadIdx.x;
    const int q = tid >> 7;
    const int e = tid & 127;
    const bool act = (e < MM);
    const int ee = act ? e : 0;
    const int i = ee / 10;
    const int j = ee - i * 10;
    const int base = blockIdx.x * 16;

    float a[8], p[8], s[8];
    float colA[8][10];

#pragma unroll
    for (int m = 0; m < 8; ++m) {
        int mat = base + q * 8 + m;
        a[m] = act ? Ain[(size_t)mat * MM + e] : 0.f;
        if (act) Am[q * 8 + m][e] = a[m];
    }
    __syncthreads();
#pragma unroll
    for (int m = 0; m < 8; ++m)
#pragma unroll
        for (int k = 0; k < 10; ++k) colA[m][k] = Am[q * 8 + m][k * 10 + j];

#pragma unroll
    for (int m = 0; m < 8; ++m) {
        p[m] = a[m];
        s[m] = a[m] + ((i == j) ? 1.f : 0.f);
    }

#pragma unroll
    for (int t = 2; t <= 14; ++t) {
        __syncthreads();
#pragma unroll
        for (int m = 0; m < 8; ++m)
            if (act) Pm[q * 8 + m][e] = p[m];
        __syncthreads();
        const float inv = 1.f / (float)t;
#pragma unroll
        for (int m = 0; m < 8; ++m) {
            float np = 0.f;
#pragma unroll
            for (int k = 0; k < 10; ++k) np += Pm[q * 8 + m][i * 10 + k] * colA[m][k];
            p[m] = np * inv;
            s[m] += p[m];
        }
    }
#pragma unroll
    for (int m = 0; m < 8; ++m) {
        int mat = base + q * 8 + m;
        if (act) Gout[(size_t)mat * MM + e] = s[m];
    }
}

// -------------------------------------------- weight transpose fp32, k-major
// Wt[(tap*CIN+ci)*COUT + co] = W[co][ci][tap]   (layer0 only)
__global__ void wtrans(const float* __restrict__ W, float* __restrict__ Wt,
                       int CIN, int COUT_) {
    int idx = blockIdx.x * 256 + threadIdx.x;
    int K = 3 * CIN;
    if (idx >= K * COUT_) return;
    int co = idx % COUT_;
    int k = idx / COUT_;
    int tap = k / CIN;
    int ci = k - tap * CIN;
    Wt[idx] = W[(size_t)(co * CIN + ci) * 3 + tap];
}

// ------------------------------- weight transpose to n-major bf16 hi/lo pair
// Wn{hi,lo}[co*1536 + tap*512 + ci] = split(W[co][ci][tap]);  CIN=COUT=512
__global__ void wtrans_bf(const float* __restrict__ W,
                          unsigned short* __restrict__ Whi,
                          unsigned short* __restrict__ Wlo) {
    int idx = blockIdx.x * 256 + threadIdx.x;  // over 512*1536
    if (idx >= 512 * 1536) return;
    int co = idx / 1536;
    int k = idx - co * 1536;
    int t = k / 512, ci = k - t * 512;
    float v = W[(size_t)(co * 512 + ci) * 3 + t];
    unsigned short h = f2bf(v);
    Whi[idx] = h;
    Wlo[idx] = f2bf(v - bf2f(h));
}

// ------------------------------------------ layer0 fp32 conv GEMM (K=300)
template <int CIN>
__global__ __launch_bounds__(256) void conv_gemm(const float* __restrict__ X,
                                                 const float* __restrict__ Wt,
                                                 const float* __restrict__ Bias,
                                                 float* __restrict__ Y,
                                                 int relu) {
    constexpr int K = 3 * CIN;
    __shared__ float As[16][132];
    __shared__ float Bs[16][128];
    const int row0 = blockIdx.x * 128;
    const int col0 = blockIdx.y * 128;
    const int tid = threadIdx.x;
    const int tx = tid & 15, ty = tid >> 4;
    float acc[8][8];
#pragma unroll
    for (int r = 0; r < 8; ++r)
#pragma unroll
        for (int c = 0; c < 8; ++c) acc[r][c] = 0.f;

    for (int k0 = 0; k0 < K; k0 += 16) {
#pragma unroll
        for (int ii = 0; ii < 8; ++ii) {
            int u = tid * 8 + ii;
            int kk = u & 15, m = u >> 4;
            int k = k0 + kk;
            float v = 0.f;
            if (k < K) {
                int tap = k / CIN;
                int ci = k - tap * CIN;
                int row = row0 + m;
                int sl = (row & 15) + tap - 1;
                if (sl >= 0 && sl < NWS) v = X[(size_t)(row + tap - 1) * CIN + ci];
            }
            As[kk][m] = v;
        }
#pragma unroll
        for (int ii = 0; ii < 8; ++ii) {
            int u = tid + ii * 256;
            int n = u & 127, kk = u >> 7;
            int k = k0 + kk;
            Bs[kk][n] = (k < K) ? Wt[(size_t)k * NCOUT + col0 + n] : 0.f;
        }
        __syncthreads();
#pragma unroll
        for (int kk = 0; kk < 16; ++kk) {
            float a[8], b[8];
#pragma unroll
            for (int r = 0; r < 8; ++r) a[r] = As[kk][ty * 8 + r];
#pragma unroll
            for (int c = 0; c < 8; ++c) b[c] = Bs[kk][tx * 8 + c];
#pragma unroll
            for (int r = 0; r < 8; ++r)
#pragma unroll
                for (int c = 0; c < 8; ++c) acc[r][c] += a[r] * b[c];
        }
        __syncthreads();
    }
    float bi[8];
#pragma unroll
    for (int c = 0; c < 8; ++c) bi[c] = Bias[col0 + tx * 8 + c];
#pragma unroll
    for (int r = 0; r < 8; ++r) {
        size_t off = (size_t)(row0 + ty * 8 + r) * NCOUT + col0 + tx * 8;
#pragma unroll
        for (int c = 0; c < 8; ++c) {
            float v = acc[r][c] + bi[c];
            Y[off + c] = relu ? fmaxf(v, 0.f) : v;
        }
    }
}

// --------------------------- split-bf16 MFMA conv GEMM (layers 1-4, CIN=512)
// M=32768, N=512, K=1536 (3 taps x 512 ci). 128x128 tile, 4 waves, each wave
// 64x64 = 4x4 frags of 16x16x32. Per k-chunk(32): stage A fp32->hi/lo split
// in-register + B hi/lo (pre-split), swizzled LDS; 48 MFMAs/wave.
template <int RELU>
__global__ __launch_bounds__(256) void conv_mfma(
    const float* __restrict__ X,
    const unsigned short* __restrict__ Whi, const unsigned short* __restrict__ Wlo,
    const float* __restrict__ Bias,
    float* __restrict__ Y) {
    __shared__ __align__(16) unsigned short AH[128 * 32];
    __shared__ __align__(16) unsigned short AL[128 * 32];
    __shared__ __align__(16) unsigned short BH[128 * 32];
    __shared__ __align__(16) unsigned short BL[128 * 32];
    const int tid = threadIdx.x;
    const int lane = tid & 63;
    const int wv = tid >> 6;
    const int wr = (wv >> 1) * 64;   // wave's 64-row block in tile
    const int wc = (wv & 1) * 64;    // wave's 64-col block
    const int row0 = blockIdx.x * 128;
    const int col0 = blockIdx.y * 128;

    f32x4 acc[4][4] = {};

    for (int t = 0; t < 3; ++t) {
        for (int c = 0; c < 512; c += 32) {
            __syncthreads();
            // stage: u in [0,512) -> row m=u>>2, k-granule g=u&3 (8 elems, 16B bf16)
#pragma unroll
            for (int rep = 0; rep < 2; ++rep) {
                int u = tid + rep * 256;
                int m = u >> 2, g = u & 3;
                int ldso = m * 32 + ((g ^ ((m >> 1) & 3)) << 3);  // swizzled slot
                int sl = (m & 15) + t - 1;                        // shifted l
                short8 vh = {}, vl = {};
                if (sl >= 0 && sl < 16) {
                    const float* src = &X[(size_t)(row0 + m + t - 1) * 512 + c + g * 8];
#pragma unroll
                    for (int e = 0; e < 8; ++e) {
                        float x = src[e];
                        unsigned short h = f2bf(x);
                        vh[e] = (short)h;
                        vl[e] = (short)f2bf(x - bf2f(h));
                    }
                }
                *(short8*)&AH[ldso] = vh;
                *(short8*)&AL[ldso] = vl;
                size_t ba = (size_t)(col0 + m) * 1536 + t * 512 + c + g * 8;
                *(short8*)&BH[ldso] = *(const short8*)&Whi[ba];
                *(short8*)&BL[ldso] = *(const short8*)&Wlo[ba];
            }
            __syncthreads();
            // fragments: operand index (row/col) = lane&15, k-granule = lane>>4
            short8 ah[4], al[4], bh[4], bl[4];
#pragma unroll
            for (int mt = 0; mt < 4; ++mt) {
                int m = wr + mt * 16 + (lane & 15);
                int off = m * 32 + ((((lane >> 4) ^ ((m >> 1) & 3))) << 3);
                ah[mt] = *(const short8*)&AH[off];
                al[mt] = *(const short8*)&AL[off];
            }
#pragma unroll
            for (int nt = 0; nt < 4; ++nt) {
                int n = wc + nt * 16 + (lane & 15);
                int off = n * 32 + ((((lane >> 4) ^ ((n >> 1) & 3))) << 3);
                bh[nt] = *(const short8*)&BH[off];
                bl[nt] = *(const short8*)&BL[off];
            }
#pragma unroll
            for (int mt = 0; mt < 4; ++mt)
#pragma unroll
                for (int nt = 0; nt < 4; ++nt) {
                    acc[mt][nt] = __builtin_amdgcn_mfma_f32_16x16x32_bf16(ah[mt], bl[nt], acc[mt][nt], 0, 0, 0);
                    acc[mt][nt] = __builtin_amdgcn_mfma_f32_16x16x32_bf16(al[mt], bh[nt], acc[mt][nt], 0, 0, 0);
                    acc[mt][nt] = __builtin_amdgcn_mfma_f32_16x16x32_bf16(ah[mt], bh[nt], acc[mt][nt], 0, 0, 0);
                }
        }
    }
    // epilogue: D[row=4*(lane>>4)+i][col=lane&15] per 16x16 frag (measured map)
    float bcol[4];
#pragma unroll
    for (int nt = 0; nt < 4; ++nt) bcol[nt] = Bias[col0 + wc + nt * 16 + (lane & 15)];
#pragma unroll
    for (int mt = 0; mt < 4; ++mt)
#pragma unroll
        for (int nt = 0; nt < 4; ++nt) {
            int gcol = col0 + wc + nt * 16 + (lane & 15);
#pragma unroll
            for (int i = 0; i < 4; ++i) {
                int grow = row0 + wr + mt * 16 + 4 * (lane >> 4) + i;
                float v = acc[mt][nt][i] + bcol[nt];
                if (RELU) v = fmaxf(v, 0.f);
                Y[(size_t)grow * 512 + gcol] = v;
            }
        }
}

extern "C" void kernel_launch(void* const* d_in, const int* in_sizes, int n_in,
                              void* d_out, int out_size, void* d_ws, size_t ws_size,
                              hipStream_t stream) {
    (void)in_sizes; (void)n_in; (void)out_size; (void)ws_size;
    const float* z     = (const float*)d_in[0];
    const float* basis = (const float*)d_in[1];
    const float* W0 = (const float*)d_in[2];  const float* b0 = (const float*)d_in[3];
    const float* W1 = (const float*)d_in[4];  const float* b1 = (const float*)d_in[5];
    const float* W2 = (const float*)d_in[6];  const float* b2 = (const float*)d_in[7];
    const float* W3 = (const float*)d_in[8];  const float* b3 = (const float*)d_in[9];
    const float* W4 = (const float*)d_in[10]; const float* b4 = (const float*)d_in[11];
    float* out = (float*)d_out;
    char* ws = (char*)d_ws;
    const size_t MB = 1ull << 20;

    // ws layout (67MB total):
    //   [0,64M)   bufA: fp32 layer ping buffer [32768][512]
    //             gfeat [32768][100] fp32 lives at ws+0 (dead before bufA
    //             is first written by the L1 conv)
    //   [64M,..)  Wt0 fp32 (614KB, layer0 only; dead before Wn written)
    //             then Wnhi (1.5MB) / Wnlo (1.5MB)
    // d_out (64MB) hosts lieA [32768][100] (dead after expm), then serves as
    // the second ping buffer; final layer writes d_out.
    float* bufA  = (float*)ws;
    float* gfeat = (float*)ws;
    float* lieA  = out;
    float* Wt0   = (float*)(ws + 64 * MB);
    unsigned short* Wnhi = (unsigned short*)(ws + 64 * MB);
    unsigned short* Wnlo = (unsigned short*)(ws + 64 * MB + 1572864);

    // 1. einsum -> lieA (in d_out)
    lie_gemm<<<dim3(16, 16), 256, 0, stream>>>(z, basis, lieA);
    // 2. expm -> gfeat (in ws)
    expm_kernel<<<2048, 256, 0, stream>>>(lieA, gfeat);

    // 3. layer0 fp32 (K=300): gfeat -> d_out (lieA dead)
    wtrans<<<(300 * 512 + 255) / 256, 256, 0, stream>>>(W0, Wt0, 100, 512);
    conv_gemm<100><<<dim3(256, 4), 256, 0, stream>>>(gfeat, Wt0, b0, out, 1);

    // 4. layers 1-4 via split-bf16 MFMA; ping-pong d_out <-> bufA
    wtrans_bf<<<3072, 256, 0, stream>>>(W1, Wnhi, Wnlo);
    conv_mfma<1><<<dim3(256, 4), 256, 0, stream>>>(out, Wnhi, Wnlo, b1, bufA);
    wtrans_bf<<<3072, 256, 0, stream>>>(W2, Wnhi, Wnlo);
    conv_mfma<1><<<dim3(256, 4), 256, 0, stream>>>(bufA, Wnhi, Wnlo, b2, out);
    wtrans_bf<<<3072, 256, 0, stream>>>(W3, Wnhi, Wnlo);
    conv_mfma<1><<<dim3(256, 4), 256, 0, stream>>>(out, Wnhi, Wnlo, b3, bufA);
    wtrans_bf<<<3072, 256, 0, stream>>>(W4, Wnhi, Wnlo);
    conv_mfma<0><<<dim3(256, 4), 256, 0, stream>>>(bufA, Wnhi, Wnlo, b4, out);
}

// Round 9
// 1082.951 us; speedup vs baseline: 1.1371x; 1.1371x over previous
//
#include <hip/hip_runtime.h>

// LieGroupDecoder MI355X — round 2: all-MFMA conv stack, hi/lo pair activations.
//
// Pipeline (single static path, ws need = 67MB):
//   lie_gemm(fp32 -> lieA in d_out) -> expm(-> gfeat PAIR, zero-padded to 128
//   cols, in ws) -> 5x conv_mfma (split-bf16 hh+hl+lh, fp32 acc):
//     L0: CINP=128 (K=384, W0 zero-padded)  gfeat -> PA
//     L1..L3: CINP=512 (K=1536)             PA <-> PB ping-pong
//     L4: CINP=512, fp32 epilogue           PB -> d_out
// Activations travel as bf16 hi/lo PAIR buffers (split once in the producer's
// epilogue, NOT per-consume in staging — staging is pure 16B vector copies).
// r1c post-mortem: in-staging split was ~320 VALU cyc/chunk vs 233 MFMA cyc
// (critical path), and re-split each row 4x (once per column tile).
//
// HW-validated in r1c (passed, absmax 9.8e-4): MFMA A/B fragment convention
// (operand index = lane&15, k-contiguous-8 per lane), C/D map
// (col=lane&15, row=4*(lane>>4)+reg), LDS granule swizzle slot=g^((m>>1)&3)
// applied on both write and read sides.

typedef __attribute__((ext_vector_type(8))) short short8;
typedef __attribute__((ext_vector_type(4))) float f32x4;

#define NWS 16
#define ZD 512
#define MM 100

static __device__ __forceinline__ unsigned short f2bf(float f) {
    union { float f; unsigned u; } x; x.f = f;
    unsigned r = x.u + 0x7fffu + ((x.u >> 16) & 1u);  // RNE
    return (unsigned short)(r >> 16);
}
static __device__ __forceinline__ float bf2f(unsigned short b) {
    union { unsigned u; float f; } x; x.u = ((unsigned)b) << 16; return x.f;
}

// ------------------------------------------------------------- lie einsum GEMM
__global__ __launch_bounds__(256) void lie_gemm(const float* __restrict__ Z,
                                                const float* __restrict__ Basis,
                                                float* __restrict__ Out) {
    __shared__ float As[16][132];
    __shared__ float Bs[16][128];
    const int w = blockIdx.y;
    const int row0 = blockIdx.x * 128;
    const int tid = threadIdx.x;
    const int tx = tid & 15, ty = tid >> 4;
    float acc[8][8];
#pragma unroll
    for (int r = 0; r < 8; ++r)
#pragma unroll
        for (int c = 0; c < 8; ++c) acc[r][c] = 0.f;

    for (int k0 = 0; k0 < ZD; k0 += 16) {
#pragma unroll
        for (int ii = 0; ii < 8; ++ii) {
            int u = tid * 8 + ii;
            int kk = u & 15, m = u >> 4;
            As[kk][m] = Z[(size_t)((row0 + m) * NWS + w) * ZD + (k0 + kk)];
        }
#pragma unroll
        for (int ii = 0; ii < 8; ++ii) {
            int u = tid + ii * 256;
            int n = u & 127, kk = u >> 7;
            Bs[kk][n] = (n < MM) ? Basis[(size_t)(w * ZD + k0 + kk) * MM + n] : 0.f;
        }
        __syncthreads();
#pragma unroll
        for (int kk = 0; kk < 16; ++kk) {
            float a[8], b[8];
#pragma unroll
            for (int r = 0; r < 8; ++r) a[r] = As[kk][ty * 8 + r];
#pragma unroll
            for (int c = 0; c < 8; ++c) b[c] = Bs[kk][tx * 8 + c];
#pragma unroll
            for (int r = 0; r < 8; ++r)
#pragma unroll
                for (int c = 0; c < 8; ++c) acc[r][c] += a[r] * b[c];
        }
        __syncthreads();
    }
#pragma unroll
    for (int r = 0; r < 8; ++r) {
        int b = row0 + ty * 8 + r;
#pragma unroll
        for (int c = 0; c < 8; ++c) {
            int col = tx * 8 + c;
            if (col < MM) Out[(size_t)(b * NWS + w) * MM + col] = acc[r][c];
        }
    }
}

// ------------------------------------------------------------------ expm(10x10)
// 16 matrices/block; thread owns elem (i,j) of 8 matrices. Output: hi/lo bf16
// pair, zero-padded to 128 cols (pad lanes e in [100,128) write 0).
__global__ __launch_bounds__(256) void expm_kernel(const float* __restrict__ Ain,
                                                   unsigned short* __restrict__ Ghi,
                                                   unsigned short* __restrict__ Glo) {
    __shared__ float Pm[16][104];
    __shared__ float Am[16][104];
    const int tid = threadIdx.x;
    const int q = tid >> 7;
    const int e = tid & 127;
    const bool act = (e < MM);
    const int ee = act ? e : 0;
    const int i = ee / 10;
    const int j = ee - i * 10;
    const int base = blockIdx.x * 16;

    float a[8], p[8], s[8];
    float colA[8][10];

#pragma unroll
    for (int m = 0; m < 8; ++m) {
        int mat = base + q * 8 + m;
        a[m] = act ? Ain[(size_t)mat * MM + e] : 0.f;
        if (act) Am[q * 8 + m][e] = a[m];
    }
    __syncthreads();
#pragma unroll
    for (int m = 0; m < 8; ++m)
#pragma unroll
        for (int k = 0; k < 10; ++k) colA[m][k] = Am[q * 8 + m][k * 10 + j];

#pragma unroll
    for (int m = 0; m < 8; ++m) {
        p[m] = a[m];
        s[m] = a[m] + ((i == j) ? 1.f : 0.f);
    }

#pragma unroll
    for (int t = 2; t <= 14; ++t) {
        __syncthreads();
#pragma unroll
        for (int m = 0; m < 8; ++m)
            if (act) Pm[q * 8 + m][e] = p[m];
        __syncthreads();
        const float inv = 1.f / (float)t;
#pragma unroll
        for (int m = 0; m < 8; ++m) {
            float np = 0.f;
#pragma unroll
            for (int k = 0; k < 10; ++k) np += Pm[q * 8 + m][i * 10 + k] * colA[m][k];
            p[m] = np * inv;
            s[m] += p[m];
        }
    }
#pragma unroll
    for (int m = 0; m < 8; ++m) {
        size_t off = (size_t)(base + q * 8 + m) * 128 + e;
        float v = act ? s[m] : 0.f;  // pad lanes write 0
        unsigned short h = f2bf(v);
        Ghi[off] = h;
        Glo[off] = f2bf(v - bf2f(h));
    }
}

// -------------------- weight transpose to n-major bf16 hi/lo pair, zero-padded
// Wn{hi,lo}[co*(3*CINP) + t*CINP + ci] = split(W[co][ci][t]), 0 for ci>=CIN_REAL
template <int CIN_REAL, int CINP>
__global__ void wtrans_bf(const float* __restrict__ W,
                          unsigned short* __restrict__ Whi,
                          unsigned short* __restrict__ Wlo) {
    int idx = blockIdx.x * 256 + threadIdx.x;  // over 512*3*CINP
    if (idx >= 512 * 3 * CINP) return;
    int co = idx / (3 * CINP);
    int k = idx - co * (3 * CINP);
    int t = k / CINP, ci = k - t * CINP;
    float v = (ci < CIN_REAL) ? W[(size_t)(co * CIN_REAL + ci) * 3 + t] : 0.f;
    unsigned short h = f2bf(v);
    Whi[idx] = h;
    Wlo[idx] = f2bf(v - bf2f(h));
}

// ----------------------------- split-bf16 MFMA conv GEMM (pair-in, all layers)
// M=32768, N=512, K=3*CINP. 128x128 tile, 4 waves, each wave 64x64 = 4x4 frags
// of 16x16x32. Per k-chunk(32): stage A/B hi+lo tiles as pure 16B copies into
// granule-swizzled LDS; 48 MFMAs/wave. Epilogue: PAIR_OUT ? relu+split pair :
// fp32 (+optional relu).
template <int RELU, int CINP, int PAIR_OUT>
__global__ __launch_bounds__(256) void conv_mfma(
    const unsigned short* __restrict__ Xhi, const unsigned short* __restrict__ Xlo,
    const unsigned short* __restrict__ Whi, const unsigned short* __restrict__ Wlo,
    const float* __restrict__ Bias,
    unsigned short* __restrict__ Yhi, unsigned short* __restrict__ Ylo,
    float* __restrict__ Yf) {
    __shared__ __align__(16) unsigned short AH[128 * 32];
    __shared__ __align__(16) unsigned short AL[128 * 32];
    __shared__ __align__(16) unsigned short BH[128 * 32];
    __shared__ __align__(16) unsigned short BL[128 * 32];
    const int tid = threadIdx.x;
    const int lane = tid & 63;
    const int wv = tid >> 6;
    const int wr = (wv >> 1) * 64;   // wave's 64-row block in tile
    const int wc = (wv & 1) * 64;    // wave's 64-col block
    const int row0 = blockIdx.x * 128;
    const int col0 = blockIdx.y * 128;

    f32x4 acc[4][4] = {};

    for (int t = 0; t < 3; ++t) {
        for (int c = 0; c < CINP; c += 32) {
            __syncthreads();
            // stage: u in [0,512) -> row m=u>>2, k-granule g=u&3 (8 bf16 = 16B)
#pragma unroll
            for (int rep = 0; rep < 2; ++rep) {
                int u = tid + rep * 256;
                int m = u >> 2, g = u & 3;
                int ldso = m * 32 + ((g ^ ((m >> 1) & 3)) << 3);  // swizzled slot
                int sl = (m & 15) + t - 1;                        // shifted l
                short8 vh = {}, vl = {};
                if (sl >= 0 && sl < 16) {
                    size_t ga = (size_t)(row0 + m + t - 1) * CINP + c + g * 8;
                    vh = *(const short8*)&Xhi[ga];
                    vl = *(const short8*)&Xlo[ga];
                }
                *(short8*)&AH[ldso] = vh;
                *(short8*)&AL[ldso] = vl;
                size_t ba = (size_t)(col0 + m) * (3 * CINP) + t * CINP + c + g * 8;
                *(short8*)&BH[ldso] = *(const short8*)&Whi[ba];
                *(short8*)&BL[ldso] = *(const short8*)&Wlo[ba];
            }
            __syncthreads();
            // fragments: operand index (row/col) = lane&15, k-granule = lane>>4
            short8 ah[4], al[4], bh[4], bl[4];
#pragma unroll
            for (int mt = 0; mt < 4; ++mt) {
                int m = wr + mt * 16 + (lane & 15);
                int off = m * 32 + ((((lane >> 4) ^ ((m >> 1) & 3))) << 3);
                ah[mt] = *(const short8*)&AH[off];
                al[mt] = *(const short8*)&AL[off];
            }
#pragma unroll
            for (int nt = 0; nt < 4; ++nt) {
                int n = wc + nt * 16 + (lane & 15);
                int off = n * 32 + ((((lane >> 4) ^ ((n >> 1) & 3))) << 3);
                bh[nt] = *(const short8*)&BH[off];
                bl[nt] = *(const short8*)&BL[off];
            }
#pragma unroll
            for (int mt = 0; mt < 4; ++mt)
#pragma unroll
                for (int nt = 0; nt < 4; ++nt) {
                    acc[mt][nt] = __builtin_amdgcn_mfma_f32_16x16x32_bf16(ah[mt], bl[nt], acc[mt][nt], 0, 0, 0);
                    acc[mt][nt] = __builtin_amdgcn_mfma_f32_16x16x32_bf16(al[mt], bh[nt], acc[mt][nt], 0, 0, 0);
                    acc[mt][nt] = __builtin_amdgcn_mfma_f32_16x16x32_bf16(ah[mt], bh[nt], acc[mt][nt], 0, 0, 0);
                }
        }
    }
    // epilogue: D[row=4*(lane>>4)+i][col=lane&15] per 16x16 frag (measured map)
    float bcol[4];
#pragma unroll
    for (int nt = 0; nt < 4; ++nt) bcol[nt] = Bias[col0 + wc + nt * 16 + (lane & 15)];
#pragma unroll
    for (int mt = 0; mt < 4; ++mt)
#pragma unroll
        for (int nt = 0; nt < 4; ++nt) {
            int gcol = col0 + wc + nt * 16 + (lane & 15);
#pragma unroll
            for (int i = 0; i < 4; ++i) {
                int grow = row0 + wr + mt * 16 + 4 * (lane >> 4) + i;
                float v = acc[mt][nt][i] + bcol[nt];
                if (RELU) v = fmaxf(v, 0.f);
                size_t off = (size_t)grow * 512 + gcol;
                if (PAIR_OUT) {
                    unsigned short h = f2bf(v);
                    Yhi[off] = h;
                    Ylo[off] = f2bf(v - bf2f(h));
                } else {
                    Yf[off] = v;
                }
            }
        }
}

extern "C" void kernel_launch(void* const* d_in, const int* in_sizes, int n_in,
                              void* d_out, int out_size, void* d_ws, size_t ws_size,
                              hipStream_t stream) {
    (void)in_sizes; (void)n_in; (void)out_size; (void)ws_size;
    const float* z     = (const float*)d_in[0];
    const float* basis = (const float*)d_in[1];
    const float* W0 = (const float*)d_in[2];  const float* b0 = (const float*)d_in[3];
    const float* W1 = (const float*)d_in[4];  const float* b1 = (const float*)d_in[5];
    const float* W2 = (const float*)d_in[6];  const float* b2 = (const float*)d_in[7];
    const float* W3 = (const float*)d_in[8];  const float* b3 = (const float*)d_in[9];
    const float* W4 = (const float*)d_in[10]; const float* b4 = (const float*)d_in[11];
    float* out = (float*)d_out;
    char* ws = (char*)d_ws;
    const size_t MB = 1ull << 20;

    // Buffers (ws need = 67MB; same footprint that passed in r1c):
    //   PA pair = d_out region: hi @ d_out+0, lo @ d_out+32M.
    //     (lieA fp32 13MB @ d_out+0 is dead after expm, before L0 writes PA.)
    //   PB pair = ws: hi @ ws+0, lo @ ws+32M.
    //     (gfeat pair 8M+8M @ ws+0/ws+8M is dead after L0, before L1 writes PB.)
    //   Wn slot @ ws+64M: L0 uses 768K+768K; L1..L4 reuse with 1.5M+1.5M
    //     (strictly sequential lifetimes, stream-ordered).
    //   Final: L4 reads PB (ws), writes fp32 d_out (PA dead) — no aliasing.
    float* lieA = out;
    unsigned short* Ghi = (unsigned short*)(ws);
    unsigned short* Glo = (unsigned short*)(ws + 8 * MB);
    unsigned short* PAhi = (unsigned short*)((char*)d_out);
    unsigned short* PAlo = (unsigned short*)((char*)d_out + 32 * MB);
    unsigned short* PBhi = (unsigned short*)(ws);
    unsigned short* PBlo = (unsigned short*)(ws + 32 * MB);
    unsigned short* Wnhi = (unsigned short*)(ws + 64 * MB);
    unsigned short* Wnlo = (unsigned short*)(ws + 64 * MB + 1572864);

    // 1. einsum -> lieA (in d_out)
    lie_gemm<<<dim3(16, 16), 256, 0, stream>>>(z, basis, lieA);
    // 2. expm -> gfeat pair, zero-padded to 128 cols (in ws)
    expm_kernel<<<2048, 256, 0, stream>>>(lieA, Ghi, Glo);

    // 3. L0: CINP=128 (K=384), gfeat -> PA (d_out region; lieA dead)
    wtrans_bf<100, 128><<<768, 256, 0, stream>>>(W0, Wnhi, Wnlo);
    conv_mfma<1, 128, 1><<<dim3(256, 4), 256, 0, stream>>>(Ghi, Glo, Wnhi, Wnlo, b0, PAhi, PAlo, nullptr);

    // 4. L1..L3: CINP=512, ping-pong PA <-> PB
    wtrans_bf<512, 512><<<3072, 256, 0, stream>>>(W1, Wnhi, Wnlo);
    conv_mfma<1, 512, 1><<<dim3(256, 4), 256, 0, stream>>>(PAhi, PAlo, Wnhi, Wnlo, b1, PBhi, PBlo, nullptr);
    wtrans_bf<512, 512><<<3072, 256, 0, stream>>>(W2, Wnhi, Wnlo);
    conv_mfma<1, 512, 1><<<dim3(256, 4), 256, 0, stream>>>(PBhi, PBlo, Wnhi, Wnlo, b2, PAhi, PAlo, nullptr);
    wtrans_bf<512, 512><<<3072, 256, 0, stream>>>(W3, Wnhi, Wnlo);
    conv_mfma<1, 512, 1><<<dim3(256, 4), 256, 0, stream>>>(PAhi, PAlo, Wnhi, Wnlo, b3, PBhi, PBlo, nullptr);

    // 5. L4: reads PB (ws), writes fp32 d_out
    wtrans_bf<512, 512><<<3072, 256, 0, stream>>>(W4, Wnhi, Wnlo);
    conv_mfma<0, 512, 0><<<dim3(256, 4), 256, 0, stream>>>(PBhi, PBlo, Wnhi, Wnlo, b4, nullptr, nullptr, out);
}

// Round 11
// 969.774 us; speedup vs baseline: 1.2698x; 1.1167x over previous
//
#include <hip/hip_runtime.h>

// LieGroupDecoder MI355X — round 3: conv_mfma staging via global_load_lds +
// XCD-chunked block swizzle. Same 2-barrier/chunk template as r2 (passed,
// absmax 9.77e-4); only the staging data path and block->tile map changed.
//
// r2 post-mortem: MfmaUtil 33 / VALU 15 / conflicts 0 / occ 22.5 -> ~50% of
// cycles are stage-drain (vmcnt+lgkm serialized before each barrier), and
// FETCH=288MB (4x A re-fetch across XCD L2s).
// Fixes: (1) global_load_lds w=16 with PRE-SWIZZLED per-lane source (m173) —
// LDS stays linear, swizzle moves into which global granule each lane loads;
// halo lanes exec-mask off the load and ds_write zeros. (2) bijective
// XCD-chunk swizzle: e=(bid&7)*128+(bid>>3), r=e>>2, c=e&3 — each XCD owns
// 32 row-tiles, col-tiles adjacent -> A fetched once per XCD.

typedef __attribute__((ext_vector_type(8))) short short8;
typedef __attribute__((ext_vector_type(4))) float f32x4;

#define NWS 16
#define ZD 512
#define MM 100

#define GLDS(SRC, DST)                                                        \
    __builtin_amdgcn_global_load_lds(                                         \
        (const __attribute__((address_space(1))) void*)(SRC),                 \
        (__attribute__((address_space(3))) void*)(DST), 16, 0, 0)

static __device__ __forceinline__ unsigned short f2bf(float f) {
    union { float f; unsigned u; } x; x.f = f;
    unsigned r = x.u + 0x7fffu + ((x.u >> 16) & 1u);  // RNE
    return (unsigned short)(r >> 16);
}
static __device__ __forceinline__ float bf2f(unsigned short b) {
    union { unsigned u; float f; } x; x.u = ((unsigned)b) << 16; return x.f;
}

// ------------------------------------------------------------- lie einsum GEMM
__global__ __launch_bounds__(256) void lie_gemm(const float* __restrict__ Z,
                                                const float* __restrict__ Basis,
                                                float* __restrict__ Out) {
    __shared__ float As[16][132];
    __shared__ float Bs[16][128];
    const int w = blockIdx.y;
    const int row0 = blockIdx.x * 128;
    const int tid = threadIdx.x;
    const int tx = tid & 15, ty = tid >> 4;
    float acc[8][8];
#pragma unroll
    for (int r = 0; r < 8; ++r)
#pragma unroll
        for (int c = 0; c < 8; ++c) acc[r][c] = 0.f;

    for (int k0 = 0; k0 < ZD; k0 += 16) {
#pragma unroll
        for (int ii = 0; ii < 8; ++ii) {
            int u = tid * 8 + ii;
            int kk = u & 15, m = u >> 4;
            As[kk][m] = Z[(size_t)((row0 + m) * NWS + w) * ZD + (k0 + kk)];
        }
#pragma unroll
        for (int ii = 0; ii < 8; ++ii) {
            int u = tid + ii * 256;
            int n = u & 127, kk = u >> 7;
            Bs[kk][n] = (n < MM) ? Basis[(size_t)(w * ZD + k0 + kk) * MM + n] : 0.f;
        }
        __syncthreads();
#pragma unroll
        for (int kk = 0; kk < 16; ++kk) {
            float a[8], b[8];
#pragma unroll
            for (int r = 0; r < 8; ++r) a[r] = As[kk][ty * 8 + r];
#pragma unroll
            for (int c = 0; c < 8; ++c) b[c] = Bs[kk][tx * 8 + c];
#pragma unroll
            for (int r = 0; r < 8; ++r)
#pragma unroll
                for (int c = 0; c < 8; ++c) acc[r][c] += a[r] * b[c];
        }
        __syncthreads();
    }
#pragma unroll
    for (int r = 0; r < 8; ++r) {
        int b = row0 + ty * 8 + r;
#pragma unroll
        for (int c = 0; c < 8; ++c) {
            int col = tx * 8 + c;
            if (col < MM) Out[(size_t)(b * NWS + w) * MM + col] = acc[r][c];
        }
    }
}

// ------------------------------------------------------------------ expm(10x10)
// Output: hi/lo bf16 pair, zero-padded to 128 cols.
__global__ __launch_bounds__(256) void expm_kernel(const float* __restrict__ Ain,
                                                   unsigned short* __restrict__ Ghi,
                                                   unsigned short* __restrict__ Glo) {
    __shared__ float Pm[16][104];
    __shared__ float Am[16][104];
    const int tid = threadIdx.x;
    const int q = tid >> 7;
    const int e = tid & 127;
    const bool act = (e < MM);
    const int ee = act ? e : 0;
    const int i = ee / 10;
    const int j = ee - i * 10;
    const int base = blockIdx.x * 16;

    float a[8], p[8], s[8];
    float colA[8][10];

#pragma unroll
    for (int m = 0; m < 8; ++m) {
        int mat = base + q * 8 + m;
        a[m] = act ? Ain[(size_t)mat * MM + e] : 0.f;
        if (act) Am[q * 8 + m][e] = a[m];
    }
    __syncthreads();
#pragma unroll
    for (int m = 0; m < 8; ++m)
#pragma unroll
        for (int k = 0; k < 10; ++k) colA[m][k] = Am[q * 8 + m][k * 10 + j];

#pragma unroll
    for (int m = 0; m < 8; ++m) {
        p[m] = a[m];
        s[m] = a[m] + ((i == j) ? 1.f : 0.f);
    }

#pragma unroll
    for (int t = 2; t <= 14; ++t) {
        __syncthreads();
#pragma unroll
        for (int m = 0; m < 8; ++m)
            if (act) Pm[q * 8 + m][e] = p[m];
        __syncthreads();
        const float inv = 1.f / (float)t;
#pragma unroll
        for (int m = 0; m < 8; ++m) {
            float np = 0.f;
#pragma unroll
            for (int k = 0; k < 10; ++k) np += Pm[q * 8 + m][i * 10 + k] * colA[m][k];
            p[m] = np * inv;
            s[m] += p[m];
        }
    }
#pragma unroll
    for (int m = 0; m < 8; ++m) {
        size_t off = (size_t)(base + q * 8 + m) * 128 + e;
        float v = act ? s[m] : 0.f;  // pad lanes write 0
        unsigned short h = f2bf(v);
        Ghi[off] = h;
        Glo[off] = f2bf(v - bf2f(h));
    }
}

// -------------------- weight transpose to n-major bf16 hi/lo pair, zero-padded
template <int CIN_REAL, int CINP>
__global__ void wtrans_bf(const float* __restrict__ W,
                          unsigned short* __restrict__ Whi,
                          unsigned short* __restrict__ Wlo) {
    int idx = blockIdx.x * 256 + threadIdx.x;  // over 512*3*CINP
    if (idx >= 512 * 3 * CINP) return;
    int co = idx / (3 * CINP);
    int k = idx - co * (3 * CINP);
    int t = k / CINP, ci = k - t * CINP;
    float v = (ci < CIN_REAL) ? W[(size_t)(co * CIN_REAL + ci) * 3 + t] : 0.f;
    unsigned short h = f2bf(v);
    Whi[idx] = h;
    Wlo[idx] = f2bf(v - bf2f(h));
}

// ----------------------------- split-bf16 MFMA conv GEMM (pair-in, all layers)
// M=32768, N=512, K=3*CINP. 128x128 tile, 4 waves, 4x4 frags of 16x16x32 each.
// Staging: per chunk, 8 global_load_lds w=16 per thread-slot with pre-swizzled
// per-lane source granule gsrc = gs ^ ((m>>1)&3); LDS linear. Halo lanes
// exec-mask off the load and ds_write 16B zeros. 2 barriers/chunk (compiler
// emits the vmcnt(0) drain before the post-stage barrier).
template <int RELU, int CINP, int PAIR_OUT>
__global__ __launch_bounds__(256) void conv_mfma(
    const unsigned short* __restrict__ Xhi, const unsigned short* __restrict__ Xlo,
    const unsigned short* __restrict__ Whi, const unsigned short* __restrict__ Wlo,
    const float* __restrict__ Bias,
    unsigned short* __restrict__ Yhi, unsigned short* __restrict__ Ylo,
    float* __restrict__ Yf) {
    __shared__ __align__(16) unsigned short AH[128 * 32];
    __shared__ __align__(16) unsigned short AL[128 * 32];
    __shared__ __align__(16) unsigned short BH[128 * 32];
    __shared__ __align__(16) unsigned short BL[128 * 32];
    const int tid = threadIdx.x;
    const int lane = tid & 63;
    const int wv = tid >> 6;
    const int wr = (wv >> 1) * 64;   // wave's 64-row block in tile
    const int wc = (wv & 1) * 64;    // wave's 64-col block
    // XCD-chunked bijective swizzle (nwg=1024, %8==0): each XCD gets 32
    // consecutive row-tiles; a row-tile's 4 col-tiles are temporally adjacent.
    const int bid = blockIdx.x;
    const int e = ((bid & 7) << 7) + (bid >> 3);
    const int row0 = (e >> 2) * 128;
    const int col0 = (e & 3) * 128;

    f32x4 acc[4][4] = {};

    for (int t = 0; t < 3; ++t) {
        for (int c = 0; c < CINP; c += 32) {
            __syncthreads();  // prev iteration's ds_reads done before overwrite
#pragma unroll
            for (int rep = 0; rep < 2; ++rep) {
                const int slotbase = wv * 128 + rep * 64;  // wave-uniform
                const int slot = slotbase + lane;
                const int m = slot >> 2;          // tile row
                const int gs = slot & 3;          // lds granule slot
                const int gsrc = gs ^ ((m >> 1) & 3);  // swizzled src granule
                // B: no mask
                {
                    size_t ba = (size_t)(col0 + m) * (3 * CINP) + t * CINP + c + gsrc * 8;
                    GLDS(&Whi[ba], &BH[slotbase * 8]);
                    GLDS(&Wlo[ba], &BL[slotbase * 8]);
                }
                // A: halo mask via exec (masked lanes write zeros instead)
                const int sl = (m & 15) + t - 1;
                if (sl >= 0 && sl < 16) {
                    size_t ga = (size_t)(row0 + m + t - 1) * CINP + c + gsrc * 8;
                    GLDS(&Xhi[ga], &AH[slotbase * 8]);
                    GLDS(&Xlo[ga], &AL[slotbase * 8]);
                } else {
                    short8 z = {};
                    *(short8*)&AH[slot * 8] = z;
                    *(short8*)&AL[slot * 8] = z;
                }
            }
            __syncthreads();  // compiler drains vmcnt(0)+lgkmcnt(0) here
            // fragments: operand index (row/col) = lane&15, k-granule = lane>>4
            short8 ah[4], al[4], bh[4], bl[4];
#pragma unroll
            for (int mt = 0; mt < 4; ++mt) {
                int m = wr + mt * 16 + (lane & 15);
                int off = m * 32 + ((((lane >> 4) ^ ((m >> 1) & 3))) << 3);
                ah[mt] = *(const short8*)&AH[off];
                al[mt] = *(const short8*)&AL[off];
            }
#pragma unroll
            for (int nt = 0; nt < 4; ++nt) {
                int n = wc + nt * 16 + (lane & 15);
                int off = n * 32 + ((((lane >> 4) ^ ((n >> 1) & 3))) << 3);
                bh[nt] = *(const short8*)&BH[off];
                bl[nt] = *(const short8*)&BL[off];
            }
#pragma unroll
            for (int mt = 0; mt < 4; ++mt)
#pragma unroll
                for (int nt = 0; nt < 4; ++nt) {
                    acc[mt][nt] = __builtin_amdgcn_mfma_f32_16x16x32_bf16(ah[mt], bl[nt], acc[mt][nt], 0, 0, 0);
                    acc[mt][nt] = __builtin_amdgcn_mfma_f32_16x16x32_bf16(al[mt], bh[nt], acc[mt][nt], 0, 0, 0);
                    acc[mt][nt] = __builtin_amdgcn_mfma_f32_16x16x32_bf16(ah[mt], bh[nt], acc[mt][nt], 0, 0, 0);
                }
        }
    }
    // epilogue: D[row=4*(lane>>4)+i][col=lane&15] per 16x16 frag (measured map)
    float bcol[4];
#pragma unroll
    for (int nt = 0; nt < 4; ++nt) bcol[nt] = Bias[col0 + wc + nt * 16 + (lane & 15)];
#pragma unroll
    for (int mt = 0; mt < 4; ++mt)
#pragma unroll
        for (int nt = 0; nt < 4; ++nt) {
            int gcol = col0 + wc + nt * 16 + (lane & 15);
#pragma unroll
            for (int i = 0; i < 4; ++i) {
                int grow = row0 + wr + mt * 16 + 4 * (lane >> 4) + i;
                float v = acc[mt][nt][i] + bcol[nt];
                if (RELU) v = fmaxf(v, 0.f);
                size_t off = (size_t)grow * 512 + gcol;
                if (PAIR_OUT) {
                    unsigned short h = f2bf(v);
                    Yhi[off] = h;
                    Ylo[off] = f2bf(v - bf2f(h));
                } else {
                    Yf[off] = v;
                }
            }
        }
}

extern "C" void kernel_launch(void* const* d_in, const int* in_sizes, int n_in,
                              void* d_out, int out_size, void* d_ws, size_t ws_size,
                              hipStream_t stream) {
    (void)in_sizes; (void)n_in; (void)out_size; (void)ws_size;
    const float* z     = (const float*)d_in[0];
    const float* basis = (const float*)d_in[1];
    const float* W0 = (const float*)d_in[2];  const float* b0 = (const float*)d_in[3];
    const float* W1 = (const float*)d_in[4];  const float* b1 = (const float*)d_in[5];
    const float* W2 = (const float*)d_in[6];  const float* b2 = (const float*)d_in[7];
    const float* W3 = (const float*)d_in[8];  const float* b3 = (const float*)d_in[9];
    const float* W4 = (const float*)d_in[10]; const float* b4 = (const float*)d_in[11];
    float* out = (float*)d_out;
    char* ws = (char*)d_ws;
    const size_t MB = 1ull << 20;

    // Buffers (ws need = 67MB; footprint unchanged from r2 which passed):
    //   PA pair = d_out: hi @ +0, lo @ +32M (lieA fp32 dead after expm).
    //   PB pair = ws: hi @ +0, lo @ +32M (gfeat pair @ ws[0,16M) dead after L0).
    //   Wn slot @ ws+64M (3MB, sequential lifetimes). L4: PB -> fp32 d_out.
    float* lieA = out;
    unsigned short* Ghi = (unsigned short*)(ws);
    unsigned short* Glo = (unsigned short*)(ws + 8 * MB);
    unsigned short* PAhi = (unsigned short*)((char*)d_out);
    unsigned short* PAlo = (unsigned short*)((char*)d_out + 32 * MB);
    unsigned short* PBhi = (unsigned short*)(ws);
    unsigned short* PBlo = (unsigned short*)(ws + 32 * MB);
    unsigned short* Wnhi = (unsigned short*)(ws + 64 * MB);
    unsigned short* Wnlo = (unsigned short*)(ws + 64 * MB + 1572864);

    // 1. einsum -> lieA (in d_out)
    lie_gemm<<<dim3(16, 16), 256, 0, stream>>>(z, basis, lieA);
    // 2. expm -> gfeat pair, zero-padded to 128 cols (in ws)
    expm_kernel<<<2048, 256, 0, stream>>>(lieA, Ghi, Glo);

    // 3. L0: CINP=128 (K=384), gfeat -> PA (d_out region; lieA dead)
    wtrans_bf<100, 128><<<768, 256, 0, stream>>>(W0, Wnhi, Wnlo);
    conv_mfma<1, 128, 1><<<1024, 256, 0, stream>>>(Ghi, Glo, Wnhi, Wnlo, b0, PAhi, PAlo, nullptr);

    // 4. L1..L3: CINP=512, ping-pong PA <-> PB
    wtrans_bf<512, 512><<<3072, 256, 0, stream>>>(W1, Wnhi, Wnlo);
    conv_mfma<1, 512, 1><<<1024, 256, 0, stream>>>(PAhi, PAlo, Wnhi, Wnlo, b1, PBhi, PBlo, nullptr);
    wtrans_bf<512, 512><<<3072, 256, 0, stream>>>(W2, Wnhi, Wnlo);
    conv_mfma<1, 512, 1><<<1024, 256, 0, stream>>>(PBhi, PBlo, Wnhi, Wnlo, b2, PAhi, PAlo, nullptr);
    wtrans_bf<512, 512><<<3072, 256, 0, stream>>>(W3, Wnhi, Wnlo);
    conv_mfma<1, 512, 1><<<1024, 256, 0, stream>>>(PAhi, PAlo, Wnhi, Wnlo, b3, PBhi, PBlo, nullptr);

    // 5. L4: reads PB (ws), writes fp32 d_out
    wtrans_bf<512, 512><<<3072, 256, 0, stream>>>(W4, Wnhi, Wnlo);
    conv_mfma<0, 512, 0><<<1024, 256, 0, stream>>>(PBhi, PBlo, Wnhi, Wnlo, b4, nullptr, nullptr, out);
}